// Round 1
// baseline (638.554 us; speedup 1.0000x reference)
//
#include <hip/hip_runtime.h>
#include <hip/hip_bf16.h>
#include <stdint.h>

#define Bb 128
#define Hh 256
#define Nn 2048
#define WLD 768   // 3H row stride of W
#define BN 128
#define BK 64

typedef __attribute__((ext_vector_type(8))) short bf16x8;
typedef __attribute__((ext_vector_type(4))) float f32x4;
typedef __attribute__((ext_vector_type(2))) float f32x2;
typedef __attribute__((ext_vector_type(4))) unsigned int u32x4;
typedef __attribute__((ext_vector_type(2))) unsigned int u32x2;

__device__ __forceinline__ unsigned int pack2bf(float a, float b) {
    __hip_bfloat162 h2;
    h2.x = __float2bfloat16(a);
    h2.y = __float2bfloat16(b);
    union { __hip_bfloat162 h; unsigned int u; } cv;
    cv.h = h2;
    return cv.u;
}

__device__ __forceinline__ float fast_tanh(float x) {
    // tanh(x) = 1 - 2/(e^{2x}+1); stable both tails (inf -> 1, 0 -> -1)
    float e = __expf(2.0f * x);
    return 1.0f - 2.0f * __builtin_amdgcn_rcpf(e + 1.0f);
}

// ---------------------------------------------------------------------------
// Kernel 1: per (b, n-tile of 128): logits[b, n0:n0+128] =
//   sum_h v[h] * tanh( W[h,0:512] . X[b,:,n] + bias[b,h] )
// X = concat(static, dynamic) along k. bias from decoder slice of W.
// ---------------------------------------------------------------------------
__global__ __launch_bounds__(512) void attn_main(
    const float* __restrict__ stat, const float* __restrict__ dyn,
    const float* __restrict__ dec, const float* __restrict__ vv,
    const float* __restrict__ Wg, float* __restrict__ out)
{
    // LDS: W tile [256 rows][64 bf16 = 128B], X^T tile [128 rows][64 bf16]
    __shared__ __align__(16) unsigned char sW[256 * 128];
    __shared__ __align__(16) unsigned char sX[128 * 128];
    __shared__ float s_dec[256];
    __shared__ float s_v[256];
    __shared__ float s_bias[256];
    __shared__ float s_red[512];

    const int t   = threadIdx.x;
    const int bid = blockIdx.x;
    const int b   = bid >> 4;
    const int n0  = (bid & 15) * BN;

    // ---- prologue: stage decoder row + v, compute bias[h] ----
    if (t < 256) s_dec[t] = dec[b * 256 + t];
    else         s_v[t - 256] = vv[t - 256];
    __syncthreads();
    {
        const int h = t >> 1, half = t & 1;
        const float* wr = Wg + h * WLD + 512 + half * 128;
        const float* dl = s_dec + half * 128;
        float a0 = 0.f;
        #pragma unroll 8
        for (int k4 = 0; k4 < 32; ++k4) {
            f32x4 wq = *(const f32x4*)(wr + k4 * 4);
            a0 += wq.x * dl[k4*4+0] + wq.y * dl[k4*4+1]
                + wq.z * dl[k4*4+2] + wq.w * dl[k4*4+3];
        }
        s_red[t] = a0;
    }
    __syncthreads();
    if (t < 256) s_bias[t] = s_red[2*t] + s_red[2*t+1];
    // (visibility of s_bias before epilogue is guaranteed by K-loop barriers)

    // ---- main GEMM: 8 K-steps of BK=64 ----
    const int wid = t >> 6, lane = t & 63;
    const int wm = wid >> 1, wn = wid & 1;      // wave grid 4m x 2n
    const int lc = lane & 15, lr = lane >> 4;

    f32x4 acc[4][4] = {};                        // 64x64 wave tile

    const int xkg = t >> 6;       // X staging: k-group 0..7
    const int xnp = t & 63;       // n-pair
    const int wkq = t & 15;       // W staging: k-quad within row
    const int whr = t >> 4;       // W row 0..31 (+32p)

    for (int ks = 0; ks < 8; ++ks) {
        const int kb = (ks & 3) * 64;
        const float* Xsrc = (ks < 4 ? stat : dyn) + (size_t)b * Hh * Nn;

        // global -> regs (overlaps tail of previous compute)
        f32x2 xr[8];
        #pragma unroll
        for (int j = 0; j < 8; ++j)
            xr[j] = *(const f32x2*)(Xsrc + (kb + xkg*8 + j) * Nn + n0 + 2*xnp);
        f32x4 wrg[8];
        #pragma unroll
        for (int p = 0; p < 8; ++p)
            wrg[p] = *(const f32x4*)(Wg + (whr + 32*p) * WLD + ks*64 + wkq*4);

        __syncthreads();   // previous compute phase done; LDS free

        // W tile: rows h, k-contiguous bf16, XOR-swizzled
        #pragma unroll
        for (int p = 0; p < 8; ++p) {
            int h = whr + 32*p;
            u32x2 wd;
            wd.x = pack2bf(wrg[p].x, wrg[p].y);
            wd.y = pack2bf(wrg[p].z, wrg[p].w);
            *(u32x2*)(sW + h*128 + ((wkq*8) ^ ((h & 7) << 4))) = wd;
        }
        // X^T tile: row n holds k-contiguous bf16 (transpose during store)
        {
            const int n_e = 2 * xnp;
            u32x4 we;
            we.x = pack2bf(xr[0].x, xr[1].x); we.y = pack2bf(xr[2].x, xr[3].x);
            we.z = pack2bf(xr[4].x, xr[5].x); we.w = pack2bf(xr[6].x, xr[7].x);
            *(u32x4*)(sX + n_e*128 + ((xkg*16) ^ ((n_e & 7) << 4))) = we;
            const int n_o = n_e + 1;
            u32x4 wo;
            wo.x = pack2bf(xr[0].y, xr[1].y); wo.y = pack2bf(xr[2].y, xr[3].y);
            wo.z = pack2bf(xr[4].y, xr[5].y); wo.w = pack2bf(xr[6].y, xr[7].y);
            *(u32x4*)(sX + n_o*128 + ((xkg*16) ^ ((n_o & 7) << 4))) = wo;
        }
        __syncthreads();   // tiles ready

        #pragma unroll
        for (int kf = 0; kf < 2; ++kf) {
            const int co = kf*64 + lr*16;
            bf16x8 af[4], bfr[4];
            #pragma unroll
            for (int mf = 0; mf < 4; ++mf) {
                int h = wm*64 + mf*16 + lc;
                af[mf] = *(const bf16x8*)(sW + h*128 + (co ^ ((h & 7) << 4)));
            }
            #pragma unroll
            for (int nf = 0; nf < 4; ++nf) {
                int n = wn*64 + nf*16 + lc;
                bfr[nf] = *(const bf16x8*)(sX + n*128 + (co ^ ((n & 7) << 4)));
            }
            #pragma unroll
            for (int mf = 0; mf < 4; ++mf)
                #pragma unroll
                for (int nf = 0; nf < 4; ++nf)
                    acc[mf][nf] = __builtin_amdgcn_mfma_f32_16x16x32_bf16(
                        af[mf], bfr[nf], acc[mf][nf], 0, 0, 0);
        }
    }

    // ---- epilogue: bias + tanh + v-dot, reduce over h ----
    float bias_r[16], v_r[16];
    #pragma unroll
    for (int mf = 0; mf < 4; ++mf)
        #pragma unroll
        for (int r = 0; r < 4; ++r) {
            int h = wm*64 + mf*16 + lr*4 + r;   // C/D: row=(lane>>4)*4+reg
            bias_r[mf*4+r] = s_bias[h];
            v_r[mf*4+r]    = s_v[h];
        }
    float p[4] = {0.f, 0.f, 0.f, 0.f};
    #pragma unroll
    for (int nf = 0; nf < 4; ++nf)
        #pragma unroll
        for (int mf = 0; mf < 4; ++mf)
            #pragma unroll
            for (int r = 0; r < 4; ++r) {
                float pre = acc[mf][nf][r] + bias_r[mf*4+r];
                p[nf] += v_r[mf*4+r] * fast_tanh(pre);
            }
    // sum the 4 row-groups (lanes sharing col = lane&15)
    #pragma unroll
    for (int nf = 0; nf < 4; ++nf) {
        p[nf] += __shfl_xor(p[nf], 16);
        p[nf] += __shfl_xor(p[nf], 32);
    }
    if (lane < 16) {
        #pragma unroll
        for (int nf = 0; nf < 4; ++nf)
            s_red[wm*128 + wn*64 + nf*16 + lane] = p[nf];
    }
    __syncthreads();
    if (t < 128) {
        float lg = s_red[t] + s_red[128 + t] + s_red[256 + t] + s_red[384 + t];
        out[b * Nn + n0 + t] = lg;
    }
}

// ---------------------------------------------------------------------------
// Kernel 2: in-place row softmax over N=2048, one block per batch row
// ---------------------------------------------------------------------------
__global__ __launch_bounds__(256) void softmax_rows(float* __restrict__ out)
{
    __shared__ float red[8];
    const int b = blockIdx.x, t = threadIdx.x;
    float* row = out + (size_t)b * Nn;
    float v[8];
    #pragma unroll
    for (int j = 0; j < 8; ++j) v[j] = row[t + 256 * j];
    float m = v[0];
    #pragma unroll
    for (int j = 1; j < 8; ++j) m = fmaxf(m, v[j]);
    #pragma unroll
    for (int d = 1; d < 64; d <<= 1) m = fmaxf(m, __shfl_xor(m, d));
    if ((t & 63) == 0) red[t >> 6] = m;
    __syncthreads();
    m = fmaxf(fmaxf(red[0], red[1]), fmaxf(red[2], red[3]));
    float e[8];
    float s = 0.f;
    #pragma unroll
    for (int j = 0; j < 8; ++j) { e[j] = __expf(v[j] - m); s += e[j]; }
    #pragma unroll
    for (int d = 1; d < 64; d <<= 1) s += __shfl_xor(s, d);
    if ((t & 63) == 0) red[4 + (t >> 6)] = s;
    __syncthreads();
    const float tot = red[4] + red[5] + red[6] + red[7];
    const float inv = 1.0f / tot;
    #pragma unroll
    for (int j = 0; j < 8; ++j) row[t + 256 * j] = e[j] * inv;
}

extern "C" void kernel_launch(void* const* d_in, const int* in_sizes, int n_in,
                              void* d_out, int out_size, void* d_ws, size_t ws_size,
                              hipStream_t stream) {
    const float* stat = (const float*)d_in[0];
    const float* dyn  = (const float*)d_in[1];
    const float* dec  = (const float*)d_in[2];
    const float* vv   = (const float*)d_in[3];
    const float* Wg   = (const float*)d_in[4];
    float* out = (float*)d_out;
    hipLaunchKernelGGL(attn_main, dim3(Bb * (Nn / BN)), dim3(512), 0, stream,
                       stat, dyn, dec, vv, Wg, out);
    hipLaunchKernelGGL(softmax_rows, dim3(Bb), dim3(256), 0, stream, out);
}